// Round 17
// baseline (169.496 us; speedup 1.0000x reference)
//
#include <hip/hip_runtime.h>

// MixtureOfExpertsNet: B=8388608 rows, E=4, H=16. f32 in/out.
// pred = sum_e(p_e*m_e*adj_e) / sum_e(p_e*m_e)  (softmax max-sub and /wsum cancel)
//
// R10: PWL-LUT body broke the VALU plateau (59.3 -> 35.6us). R12 (512 bins,
// RPT=8) = 34.9us. R13/R14/R15/R16 (TLP, occupancy, generations, SW pipeline)
// all null -> main kernel is ~31-32us latency-resistant stream + ~3us
// serialized prep dispatch + gap.
// R17: SINGLE dispatch. Each block builds the 512-bin PWL LUT in its own LDS:
// wave w owns expert e=w (wave-uniform weight broadcast loads), lane computes
// 8 bins (~640 one-time VALU, overlapped with first row loads). Gating uses
// raw Wg/bg s_loads + one v_mul by log2e per (row,e). Main loop = R16 body.

typedef float f32x2 __attribute__((ext_vector_type(2)));
typedef float f32x4 __attribute__((ext_vector_type(4)));

#define RPT   8
#define PIPE  3              // load-ahead distance
#define BINS  512
#define SCALE 32.0f          // BINS / 16, domain [-8, 8]

__global__ __launch_bounds__(256, 8) void moe_kernel(
    const f32x4* __restrict__ x,
    const float* __restrict__ Wg, const float* __restrict__ bg,
    const float* __restrict__ W1, const float* __restrict__ b1,
    const float* __restrict__ W2, const float* __restrict__ b2,
    float* __restrict__ out)
{
    __shared__ f32x2 lut[4 * BINS];                  // 16 KB
    const int t = threadIdx.x;
    const int base = blockIdx.x * (256 * RPT) + t;

    // issue first PIPE row loads; they complete during the LUT build
    f32x4 xv[RPT];
#pragma unroll
    for (int k = 0; k < PIPE; ++k)
        xv[k] = x[base + k * 256];

    // ---- in-block LUT build: wave w -> expert w, lane -> 8 bins ----
    {
        const int e = t >> 6;                        // wave index = expert
        const int lane = t & 63;
        float b2e = b2[e];
        float m[8], c[8];
#pragma unroll
        for (int q = 0; q < 8; ++q) { m[q] = 0.0f; c[q] = b2e; }

#pragma unroll
        for (int h2 = 0; h2 < 8; ++h2) {
            // wave-uniform addresses -> broadcast loads (L2-hit)
            f32x2 w1 = *(const f32x2*)&W1[e * 16 + 2 * h2];
            f32x2 bb = *(const f32x2*)&b1[e * 16 + 2 * h2];
            f32x2 w2 = *(const f32x2*)&W2[e * 16 + 2 * h2];
            float pm0 = w1.x * w2.x, pc0 = bb.x * w2.x;
            float pm1 = w1.y * w2.y, pc1 = bb.y * w2.y;
#pragma unroll
            for (int q = 0; q < 8; ++q) {
                float xc = ((float)(lane * 8 + q) + 0.5f) * (1.0f / SCALE) - 8.0f;
                bool a0 = fmaf(w1.x, xc, bb.x) > 0.0f;   // h = 2*h2
                m[q] += a0 ? pm0 : 0.0f;
                c[q] += a0 ? pc0 : 0.0f;
                bool a1 = fmaf(w1.y, xc, bb.y) > 0.0f;   // h = 2*h2+1
                m[q] += a1 ? pm1 : 0.0f;
                c[q] += a1 ? pc1 : 0.0f;
            }
        }
#pragma unroll
        for (int q = 0; q < 8; ++q)
            lut[e * BINS + lane * 8 + q] = (f32x2){m[q], c[q]};
    }
    __syncthreads();

    const float L2E = 1.4426950408889634f;
#pragma unroll
    for (int k = 0; k < RPT; ++k) {
        if (k + PIPE < RPT)
            xv[k + PIPE] = x[base + (k + PIPE) * 256];

        float xr[4] = {xv[k].x, xv[k].y, xv[k].z, xv[k].w};
        float xf[4]; bool ok[4];
#pragma unroll
        for (int e = 0; e < 4; ++e) {
            ok[e] = (xr[e] == xr[e]);                 // !isnan
            xf[e] = ok[e] ? xr[e] : 0.0f;
        }

        float num = 0.0f, den = 0.0f;
#pragma unroll
        for (int e = 0; e < 4; ++e) {
            // gating (Wg/bg uniform s_loads; 1 SGPR operand per fma)
            float l = fmaf(xf[0], Wg[e * 4 + 0],
                      fmaf(xf[1], Wg[e * 4 + 1],
                      fmaf(xf[2], Wg[e * 4 + 2],
                      fmaf(xf[3], Wg[e * 4 + 3], bg[e]))));
            float lg = ok[e] ? l * L2E : -__builtin_inff();
            float p = __builtin_amdgcn_exp2f(lg);     // 0 if masked

            // PWL lookup: adj_e = max(m*xf + c, 0)
            int bi = (int)fmaf(xf[e], SCALE, (float)(BINS / 2));
            bi = bi < 0 ? 0 : (bi > BINS - 1 ? BINS - 1 : bi);
            f32x2 mc = lut[e * BINS + bi];            // ds_read_b64
            float adj = fmaxf(fmaf(xf[e], mc.x, mc.y), 0.0f);

            den += p;
            num = fmaf(p, adj, num);
        }
        // den==0 only when all experts masked: num=0 -> 0*inf = NaN (matches ref)
        out[base + k * 256] = num * __builtin_amdgcn_rcpf(den);
    }
}

extern "C" void kernel_launch(void* const* d_in, const int* in_sizes, int n_in,
                              void* d_out, int out_size, void* d_ws, size_t ws_size,
                              hipStream_t stream) {
    const f32x4* x  = (const f32x4*)d_in[0];
    const float* Wg = (const float*)d_in[1];
    const float* bg = (const float*)d_in[2];
    const float* W1 = (const float*)d_in[3];
    const float* b1 = (const float*)d_in[4];
    const float* W2 = (const float*)d_in[5];
    const float* b2 = (const float*)d_in[6];
    float* out = (float*)d_out;

    int B = in_sizes[0] / 4;                   // 8388608 rows
    int blocks = B / (256 * RPT);              // 4096
    moe_kernel<<<blocks, 256, 0, stream>>>(x, Wg, bg, W1, b1, W2, b2, out);
}

// Round 18
// 34.873 us; speedup vs baseline: 4.8604x; 4.8604x over previous
//
#include <hip/hip_runtime.h>

// MixtureOfExpertsNet: B=8388608 rows, E=4, H=16. f32 in/out.
// pred = sum_e(p_e*m_e*adj_e) / sum_e(p_e*m_e)  (softmax max-sub and /wsum cancel)
//
// CHAMPION RESTORE (R12, 34.9us): PWL-LUT via prep dispatch + LDS staging.
// R10: PWL-LUT body broke the 58-74us VALU plateau (~80 slots/row vs ~370).
// R12: 512 bins + log2e fold + RPT=8 -> 34.9us.
// Exhausted levers (all null or worse vs R12):
//   R13 RPT=16 (38.9: 16 pending loads -> pressure), R14 occupancy pin (null,
//   VGPR already <=64), R15 2-batch blocks (null), R16 SW-pipelined loads
//   (null), R17 in-block LUT build (169us: scratch spill, VGPR=32, 328MB
//   write amplification + 32-way LDS write conflicts).
// Status: ~76% of measured mixed-stream ceiling (168MB @ 4.8 vs 6.3 TB/s
// achievable); residual is prep dispatch (~3us) + latency-resistant stream.

typedef float f32x2 __attribute__((ext_vector_type(2)));
typedef float f32x4 __attribute__((ext_vector_type(4)));

#define RPT   8
#define BINS  512
#define SCALE 32.0f          // BINS / 16, domain [-8, 8]

// one thread per (e, bin): m = sum_{h active at bin midpoint} w1*w2,
//                          c = b2 + sum_{h active} b1*w2
// threads 0..19 also write log2e-scaled gating consts after the LUT.
__global__ __launch_bounds__(256) void prep_kernel(
    const float* __restrict__ Wg, const float* __restrict__ bg,
    const float* __restrict__ W1, const float* __restrict__ b1,
    const float* __restrict__ W2, const float* __restrict__ b2,
    f32x2* __restrict__ lut)      // [e*BINS + bin], then 16 wgl + 4 bgl floats
{
    int i = blockIdx.x * blockDim.x + threadIdx.x;   // 0 .. 4*BINS-1
    if (i >= 4 * BINS) return;
    int e = i / BINS, bin = i & (BINS - 1);
    float xc = ((float)bin + 0.5f) * (1.0f / SCALE) - 8.0f;   // bin midpoint
    float m = 0.0f, c = b2[e];
    for (int h = 0; h < 16; ++h) {
        float w1 = W1[e * 16 + h], bb = b1[e * 16 + h], w2 = W2[e * 16 + h];
        bool active = (fmaf(w1, xc, bb) > 0.0f);     // w1==0 case falls out
        m += active ? w1 * w2 : 0.0f;
        c += active ? bb * w2 : 0.0f;
    }
    lut[e * BINS + bin] = (f32x2){m, c};

    const float L2E = 1.4426950408889634f;
    float* gp = (float*)(lut + 4 * BINS);
    if (i < 16) gp[i] = Wg[i] * L2E;                 // wgl[e*4+j]
    else if (i < 20) gp[i] = bg[i - 16] * L2E;       // bgl[e]
}

__global__ __launch_bounds__(256) void moe_kernel(
    const f32x4* __restrict__ x, const f32x2* __restrict__ lutg,
    float* __restrict__ out)
{
    __shared__ f32x2 lut[4 * BINS];                  // 16 KB
    const int t = threadIdx.x;
    const int base = blockIdx.x * (256 * RPT) + t;
    const float* gp = (const float*)(lutg + 4 * BINS);  // uniform -> s_load

    // issue all row loads first; latency hides under LUT staging + barrier
    f32x4 xv[RPT];
#pragma unroll
    for (int k = 0; k < RPT; ++k)
        xv[k] = x[base + k * 256];

    // stage LUT (16KB, L2-resident) to LDS, coalesced
    {
        const f32x4* src = (const f32x4*)lutg;
        f32x4* dst = (f32x4*)lut;
#pragma unroll
        for (int q = 0; q < 4; ++q)
            dst[q * 256 + t] = src[q * 256 + t];
    }
    __syncthreads();

#pragma unroll
    for (int k = 0; k < RPT; ++k) {
        float xr[4] = {xv[k].x, xv[k].y, xv[k].z, xv[k].w};
        float xf[4]; bool ok[4];
#pragma unroll
        for (int e = 0; e < 4; ++e) {
            ok[e] = (xr[e] == xr[e]);                 // !isnan
            xf[e] = ok[e] ? xr[e] : 0.0f;
        }

        float num = 0.0f, den = 0.0f;
#pragma unroll
        for (int e = 0; e < 4; ++e) {
            // gating (wgl/bgl uniform s_loads; 1 SGPR operand per fma)
            float lg = fmaf(xf[0], gp[e * 4 + 0],
                       fmaf(xf[1], gp[e * 4 + 1],
                       fmaf(xf[2], gp[e * 4 + 2],
                       fmaf(xf[3], gp[e * 4 + 3], gp[16 + e]))));
            lg = ok[e] ? lg : -__builtin_inff();
            float p = __builtin_amdgcn_exp2f(lg);     // 0 if masked

            // PWL lookup: adj_e = max(m*xf + c, 0)
            int bi = (int)fmaf(xf[e], SCALE, (float)(BINS / 2));
            bi = bi < 0 ? 0 : (bi > BINS - 1 ? BINS - 1 : bi);
            f32x2 mc = lut[e * BINS + bi];            // ds_read_b64
            float adj = fmaxf(fmaf(xf[e], mc.x, mc.y), 0.0f);

            den += p;
            num = fmaf(p, adj, num);
        }
        // den==0 only when all experts masked: num=0 -> 0*inf = NaN (matches ref)
        out[base + k * 256] = num * __builtin_amdgcn_rcpf(den);
    }
}

extern "C" void kernel_launch(void* const* d_in, const int* in_sizes, int n_in,
                              void* d_out, int out_size, void* d_ws, size_t ws_size,
                              hipStream_t stream) {
    const f32x4* x  = (const f32x4*)d_in[0];
    const float* Wg = (const float*)d_in[1];
    const float* bg = (const float*)d_in[2];
    const float* W1 = (const float*)d_in[3];
    const float* b1 = (const float*)d_in[4];
    const float* W2 = (const float*)d_in[5];
    const float* b2 = (const float*)d_in[6];
    float* out = (float*)d_out;
    f32x2* lut = (f32x2*)d_ws;                 // 4*BINS*8B = 16 KB + 80 B gating

    prep_kernel<<<(4 * BINS + 255) / 256, 256, 0, stream>>>(Wg, bg, W1, b1, W2, b2, lut);

    int B = in_sizes[0] / 4;                   // 8388608 rows
    int blocks = B / (256 * RPT);              // 4096
    moe_kernel<<<blocks, 256, 0, stream>>>(x, lut, out);
}